// Round 7
// baseline (1854.670 us; speedup 1.0000x reference)
//
#include <hip/hip_runtime.h>
#include <hip/hip_bf16.h>

// Problem constants (hardcoded in the reference module)
#define P 4
#define NN 100000
#define MM 50000
#define EE 400000
#define DD 128
#define ROWS 32

#define SCH 4096           // scan chunk
#define NCH 13             // ceil(MM / SCH)

typedef __attribute__((ext_vector_type(8))) short bf16x8;   // 8 bf16 in 4 VGPRs
typedef __attribute__((ext_vector_type(4))) float f32x4;    // MFMA accumulator

__device__ inline unsigned short bf16u(float x) {
    __hip_bfloat16 h = __float2bfloat16(x);                 // RNE
    return __builtin_bit_cast(unsigned short, h);
}
__device__ inline float bf16f(unsigned short u) {
    return __builtin_bit_cast(float, (unsigned)u << 16);
}

// ---------------------------------------------------------------------------
// K1: per-(s,d) pair: count original-dst degree. The atomic's RETURN value is
//     this edge's rank within its od group -> rank8[i].
__global__ __launch_bounds__(256) void k_count(const int* __restrict__ edge_dst,
                                               int* __restrict__ deg_orig,
                                               unsigned char* __restrict__ rank8) {
    int i = blockIdx.x * 256 + threadIdx.x;
    if (i >= P * P * EE) return;
    int pair = i / EE;
    int r = atomicAdd(&deg_orig[pair * MM + edge_dst[i]], 1);
    rank8[i] = (unsigned char)r;
}

// K1b: derive merged-row counts. Atomic returns give deterministic offsets:
//      grpoff[pair][od] = offset of od's edge-group within merged row m;
//      selfrank[pair][r] = rank of r within m's self list.
__global__ __launch_bounds__(256) void k_derive(const int* __restrict__ merge,
                                                const int* __restrict__ deg_orig,
                                                int* __restrict__ cnt_n,
                                                int* __restrict__ cnt_s,
                                                int* __restrict__ grpoff,
                                                int* __restrict__ selfrank) {
    int i = blockIdx.x * 256 + threadIdx.x;
    if (i >= P * P * MM) return;
    int pair = i / MM;
    int r = i - pair * MM;
    int s = pair >> 2, d = pair & 3;
    int m = (s == d) ? r : merge[i];
    grpoff[i]   = atomicAdd(&cnt_n[pair * MM + m], deg_orig[i]);
    selfrank[i] = atomicAdd(&cnt_s[pair * MM + m], 1);
}

// ---------------------------------------------------------------------------
// K2a: per-chunk partial sums (grid = 2*16*NCH = 416 blocks).
__global__ __launch_bounds__(256) void k_scan1(const int* __restrict__ cnt_n,
                                               const int* __restrict__ cnt_s,
                                               int* __restrict__ partial) {
    int blk = blockIdx.x;
    int chunk = blk % NCH, wp = blk / NCH;
    const int* cnt = ((wp >> 4) ? cnt_s : cnt_n) + (wp & 15) * MM;
    int base = chunk * SCH;
    int end = min(base + SCH, MM);
    int sum = 0;
    for (int i = base + (int)threadIdx.x; i < end; i += 256) sum += cnt[i];
    #pragma unroll
    for (int off = 32; off > 0; off >>= 1) sum += __shfl_down(sum, off);
    __shared__ int sh[4];
    if ((threadIdx.x & 63) == 0) sh[threadIdx.x >> 6] = sum;
    __syncthreads();
    if (threadIdx.x == 0) partial[blk] = sh[0] + sh[1] + sh[2] + sh[3];
}

// K2b: per-chunk exclusive scan + chunk offset; write rs.
__global__ __launch_bounds__(256) void k_scan2(const int* __restrict__ cnt_n,
                                               int* __restrict__ rs_n,
                                               const int* __restrict__ cnt_s,
                                               int* __restrict__ rs_s,
                                               const int* __restrict__ partial) {
    int blk = blockIdx.x;
    int chunk = blk % NCH, wp = blk / NCH;
    int which = wp >> 4, pair = wp & 15;
    const int* cnt = (which ? cnt_s : cnt_n) + pair * MM;
    int* rs  = (which ? rs_s : rs_n) + pair * (MM + 1);
    __shared__ int sh[256];
    __shared__ int soff;
    if (threadIdx.x == 0) {
        int o = 0;
        for (int c = 0; c < chunk; ++c) o += partial[wp * NCH + c];
        soff = o;
        if (chunk == NCH - 1) rs[MM] = o + partial[wp * NCH + chunk];
    }
    int base = chunk * SCH + (int)threadIdx.x * 16;
    int v[16]; int run = 0;
    #pragma unroll
    for (int j = 0; j < 16; ++j) {
        int i = base + j;
        int c = (i < MM) ? cnt[i] : 0;
        v[j] = run;
        run += c;
    }
    sh[threadIdx.x] = run;
    __syncthreads();
    for (int off = 1; off < 256; off <<= 1) {
        int t = (threadIdx.x >= (unsigned)off) ? sh[threadIdx.x - off] : 0;
        __syncthreads();
        sh[threadIdx.x] += t;
        __syncthreads();
    }
    int texc = sh[threadIdx.x] - run;
    int o = soff + texc;
    #pragma unroll
    for (int j = 0; j < 16; ++j) {
        int i = base + j;
        if (i < MM) rs[i] = o + v[j];
    }
}

// ---------------------------------------------------------------------------
// K2c: per-(pair,od) combo record: {base = rs_n[m] + grpoff[od], w = 1/deg}.
//      Hoists k_fill's 4 random loads/edge into one 800K-thread pass.
__global__ __launch_bounds__(256) void k_combo(const int* __restrict__ merge,
                                               const int* __restrict__ deg_orig,
                                               const int* __restrict__ grpoff,
                                               const int* __restrict__ rs_n,
                                               int2* __restrict__ combo) {
    int i = blockIdx.x * 256 + threadIdx.x;
    if (i >= P * P * MM) return;
    int pair = i / MM;
    int od = i - pair * MM;
    int s = pair >> 2, d = pair & 3;
    int m = (s == d) ? od : merge[i];
    int2 c;
    c.x = rs_n[pair * (MM + 1) + m] + grpoff[i];
    c.y = __float_as_int(1.0f / fmaxf((float)deg_orig[i], 1.0f));
    combo[i] = c;
}

// ---------------------------------------------------------------------------
// K3: scatter neigh edges into merged-dst CSR — ATOMIC-FREE, 1 random load.
//     pos = combo[od].base + rank8[i]. (src, weight) packed int2.
__global__ __launch_bounds__(256) void k_fill(const int* __restrict__ edge_src,
                                              const int* __restrict__ edge_dst,
                                              const int2* __restrict__ combo,
                                              const unsigned char* __restrict__ rank8,
                                              int2* __restrict__ csp) {
    int i = blockIdx.x * 256 + threadIdx.x;
    if (i >= P * P * EE) return;
    int pair = i / EE;
    int od = edge_dst[i];
    int2 c = combo[pair * MM + od];
    int pos = c.x + (int)rank8[i];
    int2 e; e.x = edge_src[i]; e.y = c.y;
    csp[(size_t)pair * EE + pos] = e;
}

// K3b: self-term CSR — ATOMIC-FREE. pos = rs_s[m] + selfrank[r].
__global__ __launch_bounds__(256) void k_fill_self(const int* __restrict__ merge,
                                                   const int* __restrict__ rs_s,
                                                   const int* __restrict__ selfrank,
                                                   int* __restrict__ css) {
    int i = blockIdx.x * 256 + threadIdx.x;
    if (i >= P * P * MM) return;
    int pair = i / MM;
    int r = i - pair * MM;
    int s = pair >> 2, d = pair & 3;
    int m = (s == d) ? r : merge[i];
    int pos = rs_s[pair * (MM + 1) + m] + selfrank[i];
    css[pair * MM + pos] = r;
}

// ---------------------------------------------------------------------------
// K3c: split weights into hi/lo bf16, packed fragment-ready:
//      Bpk[s][hl(2)][kchunk(32)][col(128)][8k]  (chunks 0-15 = W_self rows,
//      16-31 = W_neigh rows). 512 KB; overlaid on dead deg_orig space.
__global__ __launch_bounds__(256) void k_pack_w(const float* __restrict__ Ws,
                                                const float* __restrict__ Wn,
                                                unsigned short* __restrict__ Bpk) {
    int t = blockIdx.x * 256 + threadIdx.x;     // 4s * 32c * 128col = 16384
    if (t >= 4 * 32 * 128) return;
    int s = t >> 12;
    int rem = t & 4095;                         // c*128 + col
    int c = rem >> 7, col = rem & 127;
    const float* W = (c < 16) ? (Ws + (size_t)s * DD * DD + (c * 8) * DD + col)
                              : (Wn + (size_t)s * DD * DD + ((c - 16) * 8) * DD + col);
    size_t ohi = ((size_t)(s * 2 + 0) * 4096 + rem) * 8;
    size_t olo = ((size_t)(s * 2 + 1) * 4096 + rem) * 8;
    #pragma unroll
    for (int j = 0; j < 8; ++j) {
        float v = W[(size_t)j * DD];
        unsigned short h = bf16u(v);
        unsigned short l = bf16u(v - bf16f(h));
        Bpk[ohi + j] = h;
        Bpk[olo + j] = l;
    }
}

// ---------------------------------------------------------------------------
// K4: fused per-d kernel — round-5's proven 512-thread / 8-wave shape
//     (4 blocks/CU = 32 waves/CU), with the neigh walk widened to one
//     8-wide MASKED group per iteration (deg<=8 rows: 2 latency rounds flat,
//     no tail loop) and the s!=d self walk 2-wide masked. GEMM unchanged:
//     wave = 16-col panel x two 16-row tiles, 16x16x32 bf16 MFMA
//     (hi*hi + lo*hi + hi*lo, fp32 accum).
__global__ __launch_bounds__(512, 8) void k_fused(const float* __restrict__ x_all,
                                                  const float* __restrict__ b_all,
                                                  const int* __restrict__ rs_n_all,
                                                  const int2* __restrict__ csp_all,
                                                  const int* __restrict__ rs_s_all,
                                                  const int* __restrict__ css_all,
                                                  const unsigned short* __restrict__ Bpk,
                                                  float* __restrict__ out) {
    int d = blockIdx.y;
    int m0 = blockIdx.x * ROWS;
    int tid = threadIdx.x;
    int lane = tid & 63, wv = tid >> 6;         // wv in 0..7
    int l15 = lane & 15, kg = lane >> 4;

    // A_hi [32 rows][256 k] bf16 @0, A_lo @16384. Row stride 512 B.
    // XOR-swizzle byte ^= ((row&7)<<4) to break the 512B-stride bank conflict.
    __shared__ char lds[32768];

    f32x4 acc[2];
    f32x4 zero = {0.f, 0.f, 0.f, 0.f};
    acc[0] = zero; acc[1] = zero;

    for (int s = 0; s < P; ++s) {
        int pair = s * P + d;
        const float* x   = x_all + (size_t)s * NN * DD;
        const int* rsn   = rs_n_all + (size_t)pair * (MM + 1);
        const int2* csp  = csp_all + (size_t)pair * EE;
        const int* rss   = rs_s_all + (size_t)pair * (MM + 1);
        const int* css   = css_all + (size_t)pair * MM;

        // ---- gather: wave wv handles rows wv, wv+8, wv+16, wv+24.
        //      lane covers cols {2l, 2l+1}.
        for (int r = wv; r < ROWS; r += 8) {
            int m = m0 + r;
            float sx = 0.f, sy = 0.f, nx = 0.f, ny = 0.f;
            if (m < MM) {
                // self-scatter sum: identity on the diagonal; 2-wide masked else
                if (s == d) {
                    float2 v = ((const float2*)(x + (size_t)m * DD))[lane];
                    sx = v.x; sy = v.y;
                } else {
                    int e0 = rss[m], e1 = rss[m + 1];
                    int lim = e1 - 1;
                    for (int eb = e0; eb < e1; eb += 2) {
                        int i0 = css[min(eb, lim)];
                        int i1 = css[min(eb + 1, lim)];
                        float2 v0 = ((const float2*)(x + (size_t)i0 * DD))[lane];
                        float2 v1 = ((const float2*)(x + (size_t)i1 * DD))[lane];
                        float w1 = (eb + 1 < e1) ? 1.f : 0.f;
                        sx += v0.x + w1 * v1.x;
                        sy += v0.y + w1 * v1.y;
                    }
                }
                // weighted neigh sum: 8-wide masked groups (deg<=8 -> 1 group)
                int e0 = rsn[m], e1 = rsn[m + 1];
                int lim = e1 - 1;
                for (int eb = e0; eb < e1; eb += 8) {
                    int2 c[8];
                    #pragma unroll
                    for (int q = 0; q < 8; ++q) c[q] = csp[min(eb + q, lim)];
                    float2 v[8];
                    #pragma unroll
                    for (int q = 0; q < 8; ++q)
                        v[q] = ((const float2*)(x + (size_t)c[q].x * DD))[lane];
                    #pragma unroll
                    for (int q = 0; q < 8; ++q) {
                        float w = (eb + q < e1) ? __int_as_float(c[q].y) : 0.f;
                        nx += w * v[q].x;
                        ny += w * v[q].y;
                    }
                }
            }
            // hi/lo bf16 split -> swizzled LDS. self half k[0,128), neigh k[128,256)
            int xr = (r & 7) << 4;
            int rbase = r * 512;
            unsigned short hx = bf16u(sx), hy = bf16u(sy);
            unsigned short lx = bf16u(sx - bf16f(hx)), ly = bf16u(sy - bf16f(hy));
            *(unsigned*)(lds + rbase + ((4 * lane) ^ xr))         = hx | ((unsigned)hy << 16);
            *(unsigned*)(lds + 16384 + rbase + ((4 * lane) ^ xr)) = lx | ((unsigned)ly << 16);
            hx = bf16u(nx); hy = bf16u(ny);
            lx = bf16u(nx - bf16f(hx)); ly = bf16u(ny - bf16f(hy));
            *(unsigned*)(lds + rbase + ((256 + 4 * lane) ^ xr))         = hx | ((unsigned)hy << 16);
            *(unsigned*)(lds + 16384 + rbase + ((256 + 4 * lane) ^ xr)) = lx | ((unsigned)ly << 16);
        }
        __syncthreads();

        // ---- MFMA GEMM: acc[32][128] += A[32][256] @ [Ws[s]; Wn[s]]
        // wave wv -> cols [wv*16, wv*16+16); row tiles {0-15, 16-31}.
        {
            int row0 = l15, row1 = 16 + l15;
            int xr = (l15 & 7) << 4;
            const bf16x8* Bh = (const bf16x8*)(Bpk + (size_t)(s * 2 + 0) * 4096 * 8);
            const bf16x8* Bl = (const bf16x8*)(Bpk + (size_t)(s * 2 + 1) * 4096 * 8);
            int colbase = wv * 16 + l15;
            #pragma unroll
            for (int kk = 0; kk < 8; ++kk) {
                int c = kk * 4 + kg;
                int co = (c * 16) ^ xr;
                bf16x8 ah0 = *(const bf16x8*)(lds + row0 * 512 + co);
                bf16x8 ah1 = *(const bf16x8*)(lds + row1 * 512 + co);
                bf16x8 al0 = *(const bf16x8*)(lds + 16384 + row0 * 512 + co);
                bf16x8 al1 = *(const bf16x8*)(lds + 16384 + row1 * 512 + co);
                size_t bo = (size_t)c * 128 + colbase;
                bf16x8 bh = Bh[bo];
                bf16x8 bl = Bl[bo];
                acc[0] = __builtin_amdgcn_mfma_f32_16x16x32_bf16(ah0, bh, acc[0], 0, 0, 0);
                acc[1] = __builtin_amdgcn_mfma_f32_16x16x32_bf16(ah1, bh, acc[1], 0, 0, 0);
                acc[0] = __builtin_amdgcn_mfma_f32_16x16x32_bf16(al0, bh, acc[0], 0, 0, 0);
                acc[1] = __builtin_amdgcn_mfma_f32_16x16x32_bf16(al1, bh, acc[1], 0, 0, 0);
                acc[0] = __builtin_amdgcn_mfma_f32_16x16x32_bf16(ah0, bl, acc[0], 0, 0, 0);
                acc[1] = __builtin_amdgcn_mfma_f32_16x16x32_bf16(ah1, bl, acc[1], 0, 0, 0);
            }
        }

        // ---- bias: each contributing source row brings one b[s]
        {
            float bv = b_all[(size_t)s * DD + wv * 16 + l15];
            #pragma unroll
            for (int rt = 0; rt < 2; ++rt) {
                int mb = m0 + rt * 16 + kg * 4;
                #pragma unroll
                for (int r = 0; r < 4; ++r) {
                    int m = mb + r;
                    if (m < MM) {
                        float cf = (float)(rss[m + 1] - rss[m]);
                        acc[rt][r] += cf * bv;
                    }
                }
            }
        }
        __syncthreads();   // before next s overwrites LDS
    }

    // ---- store. D layout: col = lane&15 (+panel), row = (lane>>4)*4 + reg (+tile)
    float* outd = out + (size_t)d * MM * DD;
    #pragma unroll
    for (int rt = 0; rt < 2; ++rt) {
        #pragma unroll
        for (int r = 0; r < 4; ++r) {
            int m = m0 + rt * 16 + kg * 4 + r;
            if (m >= MM) continue;
            outd[(size_t)m * DD + wv * 16 + l15] = acc[rt][r];
        }
    }
}

// ---------------------------------------------------------------------------
extern "C" void kernel_launch(void* const* d_in, const int* in_sizes, int n_in,
                              void* d_out, int out_size, void* d_ws, size_t ws_size,
                              hipStream_t stream) {
    const float* x     = (const float*)d_in[0];   // [P][N][D]
    const float* Ws    = (const float*)d_in[1];   // [P][D][D]
    const float* Wn    = (const float*)d_in[2];   // [P][D][D]
    const float* b     = (const float*)d_in[3];   // [P][D]
    const int*   esrc  = (const int*)d_in[4];     // [P][P][E]
    const int*   edst  = (const int*)d_in[5];     // [P][P][E]
    const int*   merge = (const int*)d_in[6];     // [P][P][M]
    float* out = (float*)d_out;                   // [P][M][D]

    // workspace layout (~70.4 MB, unchanged):
    int* deg_orig = (int*)d_ws;                   // [16*M]; dead after k_combo -> Bpk
    int* cnt_n    = deg_orig + 16 * MM;           // [16*M] merged neigh counts
    int* cnt_s    = cnt_n + 16 * MM;              // [16*M] merged self counts
    int* rs_n     = cnt_s + 16 * MM;              // [16*(M+1)]
    int* rs_s     = rs_n + 16 * (MM + 1);         // [16*(M+1)]
    int2* csp     = (int2*)(rs_s + 16 * (MM + 1));// [16*E] packed (src, w)
    int* css      = (int*)(csp + (size_t)16 * EE);// [16*M]
    int* partial  = (int*)csp;                    // scan partials overlay (pre-fill)
    unsigned short* Bpk = (unsigned short*)d_ws;  // overlay on deg_orig

    // prep scratch in OUT (dead before k_fused, which fully overwrites out):
    int* grpoff   = (int*)out;                    // [16*M] 3.2 MB
    int* selfrank = grpoff + 16 * MM;             // [16*M] 3.2 MB
    unsigned char* rank8 = (unsigned char*)(selfrank + 16 * MM);  // [16*E] 6.4 MB
    int2* combo   = (int2*)(rank8 + (size_t)16 * EE);             // [16*M] 6.4 MB

    hipMemsetAsync(d_ws, 0, sizeof(int) * (size_t)16 * MM * 3, stream);  // deg+cnt_n+cnt_s

    int eblocks = (P * P * EE + 255) / 256;       // 25000
    int mblocks16 = (P * P * MM + 255) / 256;     // 3125
    k_count<<<eblocks, 256, 0, stream>>>(edst, deg_orig, rank8);
    k_derive<<<mblocks16, 256, 0, stream>>>(merge, deg_orig, cnt_n, cnt_s, grpoff, selfrank);
    k_scan1<<<2 * 16 * NCH, 256, 0, stream>>>(cnt_n, cnt_s, partial);
    k_scan2<<<2 * 16 * NCH, 256, 0, stream>>>(cnt_n, rs_n, cnt_s, rs_s, partial);
    k_combo<<<mblocks16, 256, 0, stream>>>(merge, deg_orig, grpoff, rs_n, combo);
    k_fill<<<eblocks, 256, 0, stream>>>(esrc, edst, combo, rank8, csp);
    k_fill_self<<<mblocks16, 256, 0, stream>>>(merge, rs_s, selfrank, css);
    k_pack_w<<<64, 256, 0, stream>>>(Ws, Wn, Bpk);  // overwrites deg_orig (dead)

    dim3 gfused((MM + ROWS - 1) / ROWS, P);       // (1563, 4)
    k_fused<<<gfused, 512, 0, stream>>>(x, b, rs_n, csp, rs_s, css, Bpk, out);
}